// Round 1
// 316.866 us; speedup vs baseline: 1.0161x; 1.0161x over previous
//
#include <hip/hip_runtime.h>
#include <stdint.h>
#include <math.h>

#define NN   8192
#define IND  256
#define HID  16
#define KN   6
#define SEG  8          // col segments
#define SW   (NN/SEG)   // 1024 cols per segment
#define CCOL 256        // cols per LDS chunk
#define NCH  (SW/CCOL)  // 4 chunks per block
#define TPC  (CCOL/16)  // 16 tiles per chunk
#define ZPB  16384      // float4 zero-stores per block (256 KB): whole out in one pass

typedef short s8v  __attribute__((ext_vector_type(8)));
typedef float f4v  __attribute__((ext_vector_type(4)));

__device__ __forceinline__ uint32_t bf16_rne_bits(float x) {
    const uint32_t u = __float_as_uint(x);
    return (u + 0x7FFFu + ((u >> 16) & 1u)) & 0xFFFF0000u;
}

// branch-free comparators on f64 keys (desc). v_max_f64/v_min_f64: 1 instr each.
#define CSWPD(X,i,j) { const double _h = fmax(X[i], X[j]); const double _l = fmin(X[i], X[j]); X[i] = _h; X[j] = _l; }
#define CSWPS(a,b)   { const double _h = fmax(a, b); const double _l = fmin(a, b); a = _h; b = _l; }
#define BSTAGESD(X) CSWPD(X,0,4) CSWPD(X,1,5) CSWPD(X,2,6) CSWPD(X,3,7) \
                    CSWPD(X,0,2) CSWPD(X,1,3) CSWPD(X,4,6) CSWPD(X,5,7) \
                    CSWPD(X,0,1) CSWPD(X,2,3) CSWPD(X,4,5) CSWPD(X,6,7)

// ---------------------------------------------------------------------------
// k1: h[i] = normalize(x[i] @ W^T + b), fused 3-limb bf16 split (old k1b) via
// LDS broadcast within the wave's block; also zeroes rs[i]. h never hits HBM.
// 5 packings (verified R8-R13): PA1=[hi|hi] PA2=[mid|hi] PA3=[lo|mid] (i side),
// PB1=[hi|mid] PB2=[hi|lo] (j side).
// ---------------------------------------------------------------------------
__global__ __launch_bounds__(256) void k1_embed(const float* __restrict__ x,
                                                const float* __restrict__ W,
                                                const float* __restrict__ b,
                                                float* __restrict__ rs,
                                                ushort* __restrict__ PA1,
                                                ushort* __restrict__ PA2,
                                                ushort* __restrict__ PA3,
                                                ushort* __restrict__ PB1,
                                                ushort* __restrict__ PB2)
{
    __shared__ float sh[4][16];
    const int lane = threadIdx.x & 63;
    const int wv   = threadIdx.x >> 6;
    const int row  = blockIdx.x * 4 + wv;

    const float4 xv = *(const float4*)(x + (size_t)row * IND + lane * 4);

    float acc[HID];
#pragma unroll
    for (int k = 0; k < HID; ++k) {
        const float4 wv4 = *(const float4*)(W + (size_t)k * IND + lane * 4);
        float v = xv.x * wv4.x + xv.y * wv4.y + xv.z * wv4.z + xv.w * wv4.w;
#pragma unroll
        for (int m = 32; m >= 1; m >>= 1) v += __shfl_xor(v, m, 64);
        acc[k] = v;
    }

    if (lane == 0) {
        float hv[HID];
        float ss = 0.f;
#pragma unroll
        for (int k = 0; k < HID; ++k) { hv[k] = acc[k] + b[k]; ss += hv[k] * hv[k]; }
        const float nrm = fmaxf(sqrtf(ss), 1e-12f);
#pragma unroll
        for (int k = 0; k < HID; ++k) sh[wv][k] = hv[k] / nrm;
        rs[row] = 0.f;
    }
    __syncthreads();

    if (lane < 32) {
        const int s = lane;
        const int k = s & 15;
        const float xval = sh[wv][k];
        const uint32_t hb = bf16_rne_bits(xval);
        const float r1 = xval - __uint_as_float(hb);
        const uint32_t mb = bf16_rne_bits(r1);
        const float r2 = r1 - __uint_as_float(mb);
        const uint32_t lb = bf16_rne_bits(r2);
        const ushort hi = (ushort)(hb >> 16);
        const ushort mi = (ushort)(mb >> 16);
        const ushort lo = (ushort)(lb >> 16);
        const bool f = (s < 16);
        const size_t t = (size_t)row * 32 + s;
        PA1[t] = hi;
        PA2[t] = f ? mi : hi;
        PA3[t] = f ? lo : mi;
        PB1[t] = f ? hi : mi;
        PB2[t] = f ? hi : lo;
    }
}

// ---------------------------------------------------------------------------
// p1: SINGLE scan pass. Per tile: 2 swizzled ds_read_b128 + 3-limb MFMA
// (bitwise identical to the old 2-pass values) + exact (v desc, idx asc) f64
// keys: kd = (double)v with 13-bit tie OR'd into the zero low-mantissa bits
// (tie = v<0 ? j : 8191-j; perturbation 2^-39 rel << f32 ulp, ordering exact).
// Same 21-comparator bitonic top-8 maintenance, on v_max_f64/v_min_f64.
// The ENTIRE 256 MB zero-fill of out rides the idle VMEM pipe here (16
// float4 stores/thread/chunk). Epilogue: 2-stage shfl quad merge, write 8
// sorted keys per (row,seg).
// ---------------------------------------------------------------------------
__global__ __launch_bounds__(256, 4) void p1_scan(const ushort* __restrict__ PA1,
                                                  const ushort* __restrict__ PA2,
                                                  const ushort* __restrict__ PA3,
                                                  const ushort* __restrict__ PB1,
                                                  const ushort* __restrict__ PB2,
                                                  double* __restrict__ tqd,
                                                  float4* __restrict__ outz)
{
    __shared__ s8v lds[2048];   // 32 KB: PB1 chunk | PB2 chunk

    const int tid  = threadIdx.x;
    const int lane = tid & 63;
    const int wv   = tid >> 6;
    const int seg  = blockIdx.x & (SEG - 1);
    const int row0 = (blockIdx.x >> 3) * 64 + wv * 16;
    const int n    = lane & 15;
    const int q    = lane >> 4;
    const int qs   = (q + ((n >> 1) & 3)) & 3;

    const size_t ioff = ((size_t)(row0 + n) << 5) + (q << 3);
    const s8v i1 = *(const s8v*)(PA1 + ioff);
    const s8v i2 = *(const s8v*)(PA2 + ioff);
    const s8v i3 = *(const s8v*)(PA3 + ioff);

    const float4 zf = make_float4(0.f, 0.f, 0.f, 0.f);

    double L[8];
#pragma unroll
    for (int t = 0; t < 8; ++t) L[t] = -INFINITY;

    for (int cc = 0; cc < NCH; ++cc) {
        __syncthreads();
#pragma unroll
        for (int it = 0; it < 8; ++it) {
            const int o  = it * 256 + tid;
            const int oo = o & 1023;
            const int c  = oo >> 2;
            const int qq = oo & 3;
            const int sw = (qq + ((c >> 1) & 3)) & 3;
            const ushort* src = (it < 4) ? PB1 : PB2;
            const int gcol = seg * SW + cc * CCOL + c;
            const s8v v = *(const s8v*)(src + ((size_t)gcol << 5) + (qq << 3));
            lds[((it < 4) ? 0 : 1024) + (c << 2) + sw] = v;
        }
        __syncthreads();

        // fused zero-fill of the WHOLE output: 16 stores/thread/chunk
        {
            const size_t zb = (size_t)blockIdx.x * ZPB + (size_t)cc * 4096 + tid;
#pragma unroll
            for (int z = 0; z < 16; ++z)
                outz[zb + z * 256] = zf;
        }

        const int base = (n << 2) + qs;
        const int a0   = seg * SW + cc * CCOL + (q << 2);   // col of acc[0] at tile 0
#pragma unroll 2
        for (int t = 0; t < TPC; ++t) {
            const s8v jb1 = lds[t * 64 + base];
            const s8v jb2 = lds[1024 + t * 64 + base];

            f4v acc = {0.f, 0.f, 0.f, 0.f};
            acc = __builtin_amdgcn_mfma_f32_16x16x32_bf16(jb1, i1, acc, 0, 0, 0);
            acc = __builtin_amdgcn_mfma_f32_16x16x32_bf16(jb2, i2, acc, 0, 0, 0);
            acc = __builtin_amdgcn_mfma_f32_16x16x32_bf16(jb1, i3, acc, 0, 0, 0);

            // exact (v desc, j asc) keys
            const int ca = a0 + (t << 4);
            double kd[4];
#pragma unroll
            for (int g = 0; g < 4; ++g) {
                const float v = acc[g];
                const int ja  = ca + g;
                const int tie = (v < 0.f) ? ja : (NN - 1 - ja);
                kd[g] = __longlong_as_double(__double_as_longlong((double)v) |
                                             (long long)(unsigned)tie);
            }

            // sort 4 keys desc (5 comparators)
            double s0 = kd[0], s1 = kd[1], s2 = kd[2], s3 = kd[3];
            CSWPS(s0, s1) CSWPS(s2, s3) CSWPS(s0, s2) CSWPS(s1, s3) CSWPS(s1, s2)

            // bitonic top-8 merge of sorted-8 L and sorted-4 {s0..s3}
            L[4] = fmax(L[4], s3);
            L[5] = fmax(L[5], s2);
            L[6] = fmax(L[6], s1);
            L[7] = fmax(L[7], s0);
            BSTAGESD(L)
        }
    }

    // quad merge across the 4 lanes of this row
#pragma unroll
    for (int mm = 16; mm <= 32; mm <<= 1) {
        double o[8], X[8];
#pragma unroll
        for (int t = 0; t < 8; ++t) o[t] = __shfl_xor(L[t], mm, 64);
#pragma unroll
        for (int t = 0; t < 8; ++t) X[t] = fmax(L[t], o[7 - t]);
        BSTAGESD(X)
#pragma unroll
        for (int t = 0; t < 8; ++t) L[t] = X[t];
    }

    if (q == 0) {
        double* dst = tqd + ((size_t)seg * NN + (row0 + n)) * 8;
#pragma unroll
        for (int t = 0; t < 8; ++t) dst[t] = L[t];
    }
}

// ---------------------------------------------------------------------------
// p2_merge: ONE WAVE PER ROW. 64 candidate keys (8 segs x top-8) <-> 64 lanes.
// 7 rounds of butterfly shfl-max; round 0 = self (dropped, exact top_k[:,0]
// semantics); rounds 1..6 decode (v, j) from the unique winning key and emit
// neighbors. Folds old k4: winner lane atomicAdd(rs[j]), lane0 adds the
// own-row half-sum. No scratch, no serial dependent loads, no p15/p3/k4.
// ---------------------------------------------------------------------------
__global__ __launch_bounds__(256) void p2_merge(const double* __restrict__ tqd,
                                                float* __restrict__ rs,
                                                int* __restrict__ ni,
                                                float* __restrict__ nv)
{
    const int lane = threadIdx.x & 63;
    const int wv   = threadIdx.x >> 6;
    const int row  = blockIdx.x * 4 + wv;
    const int s    = lane >> 3;
    const int t    = lane & 7;

    double key = tqd[((size_t)s * NN + row) * 8 + t];
    float sum = 0.f;

#pragma unroll
    for (int r = 0; r < 7; ++r) {
        double m = key;
#pragma unroll
        for (int mm = 1; mm < 64; mm <<= 1) {
            const double o = __shfl_xor(m, mm, 64);
            m = fmax(m, o);
        }
        const long long mb = __double_as_longlong(m);
        if (r >= 1) {
            const float v  = (float)__longlong_as_double(mb & ~0x1FFFLL);
            const int tie  = (int)(mb & 0x1FFFLL);
            const int j    = (v < 0.f) ? tie : (NN - 1 - tie);
            sum += v;
            if (__double_as_longlong(key) == mb) {      // unique winner lane
                nv[(size_t)row * KN + (r - 1)] = v;
                ni[(size_t)row * KN + (r - 1)] = j;
                atomicAdd(&rs[j], 0.5f * v);
            }
        }
        if (__double_as_longlong(key) == mb)
            key = __longlong_as_double((long long)0xFFF0000000000000LL); // -inf
    }

    if (lane == 0) atomicAdd(&rs[row], 0.5f * sum);
}

// ---------------------------------------------------------------------------
// k5: scatter normalized values into pre-zeroed dense output
// ---------------------------------------------------------------------------
__global__ __launch_bounds__(256) void k5_scatter(const int* __restrict__ nbr_idx,
                                                  const float* __restrict__ nbr_val,
                                                  const float* __restrict__ rs,
                                                  float* __restrict__ out)
{
    const int e = blockIdx.x * 256 + threadIdx.x;
    const int i = e / KN;
    const int j = nbr_idx[e];
    const float v = nbr_val[e] * 0.5f;
    const float wi = v / (rs[i] + 1e-8f);
    const float wj = v / (rs[j] + 1e-8f);
    atomicAdd(out + (size_t)i * NN + j, wi);
    atomicAdd(out + (size_t)j * NN + i, wj);
}

// ---------------------------------------------------------------------------
extern "C" void kernel_launch(void* const* d_in, const int* in_sizes, int n_in,
                              void* d_out, int out_size, void* d_ws, size_t ws_size,
                              hipStream_t stream)
{
    const float* x = (const float*)d_in[0];   // 8192 x 256
    const float* W = (const float*)d_in[1];   // 16 x 256
    const float* b = (const float*)d_in[2];   // 16
    float* out = (float*)d_out;               // 8192 x 8192

    // workspace layout (~7 MB), doubles first for 8B alignment
    double* tqd  = (double*)d_ws;                     // SEG*NN*8 keys (4 MB)
    float*  rs   = (float*)(tqd + (size_t)SEG * NN * 8);  // NN
    float*  nv   = rs + NN;                           // NN*KN
    int*    ni   = (int*)(nv + (size_t)NN * KN);      // NN*KN
    ushort* PA1  = (ushort*)(ni + (size_t)NN * KN);   // NN*32 each
    ushort* PA2  = PA1 + (size_t)NN * 32;
    ushort* PA3  = PA2 + (size_t)NN * 32;
    ushort* PB1  = PA3 + (size_t)NN * 32;
    ushort* PB2  = PB1 + (size_t)NN * 32;

    k1_embed <<<NN / 4,           256, 0, stream>>>(x, W, b, rs, PA1, PA2, PA3, PB1, PB2);
    p1_scan  <<<(NN / 64) * SEG,  256, 0, stream>>>(PA1, PA2, PA3, PB1, PB2, tqd, (float4*)out);
    p2_merge <<<NN / 4,           256, 0, stream>>>(tqd, rs, ni, nv);
    k5_scatter<<<(NN * KN) / 256, 256, 0, stream>>>(ni, nv, rs, out);
}

// Round 2
// 306.723 us; speedup vs baseline: 1.0497x; 1.0331x over previous
//
#include <hip/hip_runtime.h>
#include <stdint.h>
#include <math.h>

#define NN   8192
#define IND  256
#define HID  16
#define KN   6
#define SEG  8          // col segments
#define SW   (NN/SEG)   // 1024 cols per segment
#define CCOL 256        // cols per LDS chunk
#define NCH  (SW/CCOL)  // 4 chunks per block
#define TPC  (CCOL/16)  // 16 tiles per chunk
#define ZPB  16384      // float4 zero-stores per block (256 KB): whole out in one pass

typedef short s8v  __attribute__((ext_vector_type(8)));
typedef float f4v  __attribute__((ext_vector_type(4)));

__device__ __forceinline__ uint32_t bf16_rne_bits(float x) {
    const uint32_t u = __float_as_uint(x);
    return (u + 0x7FFFu + ((u >> 16) & 1u)) & 0xFFFF0000u;
}

// branch-free comparators on f64 keys (desc). v_max_f64/v_min_f64: 1 instr each.
#define CSWPD(X,i,j) { const double _h = fmax(X[i], X[j]); const double _l = fmin(X[i], X[j]); X[i] = _h; X[j] = _l; }
#define CSWPS(a,b)   { const double _h = fmax(a, b); const double _l = fmin(a, b); a = _h; b = _l; }
#define BSTAGESD(X) CSWPD(X,0,4) CSWPD(X,1,5) CSWPD(X,2,6) CSWPD(X,3,7) \
                    CSWPD(X,0,2) CSWPD(X,1,3) CSWPD(X,4,6) CSWPD(X,5,7) \
                    CSWPD(X,0,1) CSWPD(X,2,3) CSWPD(X,4,5) CSWPD(X,6,7)

// raw workgroup barrier with NO implicit vmcnt(0) drain (T4 / m139 pattern).
// sched_barrier(0) on both sides: rule #18 (compiler may not move mem ops
// across), correctness of cross-wave LDS handled by explicit lgkmcnt waits.
__device__ __forceinline__ void bar_nodrain() {
    __builtin_amdgcn_sched_barrier(0);
    __builtin_amdgcn_s_barrier();
    __builtin_amdgcn_sched_barrier(0);
}
__device__ __forceinline__ void wait_lgkm0() {
    asm volatile("s_waitcnt lgkmcnt(0)" ::: "memory");
    __builtin_amdgcn_sched_barrier(0);
}

// ---------------------------------------------------------------------------
// k1: h[i] = normalize(x[i] @ W^T + b), fused 3-limb bf16 split via LDS
// broadcast; also zeroes rs[i]. 5 packings (verified R8-R13):
// PA1=[hi|hi] PA2=[mid|hi] PA3=[lo|mid] (i side), PB1=[hi|mid] PB2=[hi|lo].
// ---------------------------------------------------------------------------
__global__ __launch_bounds__(256) void k1_embed(const float* __restrict__ x,
                                                const float* __restrict__ W,
                                                const float* __restrict__ b,
                                                float* __restrict__ rs,
                                                ushort* __restrict__ PA1,
                                                ushort* __restrict__ PA2,
                                                ushort* __restrict__ PA3,
                                                ushort* __restrict__ PB1,
                                                ushort* __restrict__ PB2)
{
    __shared__ float sh[4][16];
    const int lane = threadIdx.x & 63;
    const int wv   = threadIdx.x >> 6;
    const int row  = blockIdx.x * 4 + wv;

    const float4 xv = *(const float4*)(x + (size_t)row * IND + lane * 4);

    float acc[HID];
#pragma unroll
    for (int k = 0; k < HID; ++k) {
        const float4 wv4 = *(const float4*)(W + (size_t)k * IND + lane * 4);
        float v = xv.x * wv4.x + xv.y * wv4.y + xv.z * wv4.z + xv.w * wv4.w;
#pragma unroll
        for (int m = 32; m >= 1; m >>= 1) v += __shfl_xor(v, m, 64);
        acc[k] = v;
    }

    if (lane == 0) {
        float hv[HID];
        float ss = 0.f;
#pragma unroll
        for (int k = 0; k < HID; ++k) { hv[k] = acc[k] + b[k]; ss += hv[k] * hv[k]; }
        const float nrm = fmaxf(sqrtf(ss), 1e-12f);
#pragma unroll
        for (int k = 0; k < HID; ++k) sh[wv][k] = hv[k] / nrm;
        rs[row] = 0.f;
    }
    __syncthreads();

    if (lane < 32) {
        const int s = lane;
        const int k = s & 15;
        const float xval = sh[wv][k];
        const uint32_t hb = bf16_rne_bits(xval);
        const float r1 = xval - __uint_as_float(hb);
        const uint32_t mb = bf16_rne_bits(r1);
        const float r2 = r1 - __uint_as_float(mb);
        const uint32_t lb = bf16_rne_bits(r2);
        const ushort hi = (ushort)(hb >> 16);
        const ushort mi = (ushort)(mb >> 16);
        const ushort lo = (ushort)(lb >> 16);
        const bool f = (s < 16);
        const size_t t = (size_t)row * 32 + s;
        PA1[t] = hi;
        PA2[t] = f ? mi : hi;
        PA3[t] = f ? lo : mi;
        PB1[t] = f ? hi : mi;
        PB2[t] = f ? hi : lo;
    }
}

// ---------------------------------------------------------------------------
// p1: single scan pass, exact (v desc, j asc) f64 keys, 21-comparator
// bitonic top-8 per lane, 2-stage shfl quad merge.
//
// Barrier discipline (this round's change): raw s_barrier with NO vmcnt
// drain. Staging loads are issued BEFORE the zero-fill stores; vmcnt is a
// FIFO counter, so the compiler's counted vmcnt(N) before each ds_write
// retires only the (older) staging loads and leaves the zero-stores in
// flight. Stores drain under the tile loop + next chunk's stage instead of
// serializing at each __syncthreads (was ~10 us/chunk of forced drain).
// Cross-wave LDS correctness: wait_lgkm0() before the post-stage barrier
// (own ds_writes visible); pre-stage barrier needs no wait (tile-loop
// ds_reads are consumed by the sort => already retired by data dep).
// ---------------------------------------------------------------------------
__global__ __launch_bounds__(256, 4) void p1_scan(const ushort* __restrict__ PA1,
                                                  const ushort* __restrict__ PA2,
                                                  const ushort* __restrict__ PA3,
                                                  const ushort* __restrict__ PB1,
                                                  const ushort* __restrict__ PB2,
                                                  double* __restrict__ tqd,
                                                  float4* __restrict__ outz)
{
    __shared__ s8v lds[2048];   // 32 KB: PB1 chunk | PB2 chunk

    const int tid  = threadIdx.x;
    const int lane = tid & 63;
    const int wv   = tid >> 6;
    const int seg  = blockIdx.x & (SEG - 1);
    const int row0 = (blockIdx.x >> 3) * 64 + wv * 16;
    const int n    = lane & 15;
    const int q    = lane >> 4;
    const int qs   = (q + ((n >> 1) & 3)) & 3;

    const size_t ioff = ((size_t)(row0 + n) << 5) + (q << 3);
    const s8v i1 = *(const s8v*)(PA1 + ioff);
    const s8v i2 = *(const s8v*)(PA2 + ioff);
    const s8v i3 = *(const s8v*)(PA3 + ioff);

    const float4 zf = make_float4(0.f, 0.f, 0.f, 0.f);

    double L[8];
#pragma unroll
    for (int t = 0; t < 8; ++t) L[t] = -INFINITY;

    for (int cc = 0; cc < NCH; ++cc) {
        // barrier 1: all waves done READING lds for chunk cc-1
        bar_nodrain();

        // stage chunk cc (loads issued first => oldest in vmcnt FIFO)
#pragma unroll
        for (int it = 0; it < 8; ++it) {
            const int o  = it * 256 + tid;
            const int oo = o & 1023;
            const int c  = oo >> 2;
            const int qq = oo & 3;
            const int sw = (qq + ((c >> 1) & 3)) & 3;
            const ushort* src = (it < 4) ? PB1 : PB2;
            const int gcol = seg * SW + cc * CCOL + c;
            const s8v v = *(const s8v*)(src + ((size_t)gcol << 5) + (qq << 3));
            lds[((it < 4) ? 0 : 1024) + (c << 2) + sw] = v;
        }

        // own ds_writes complete, then barrier 2 — no vmcnt drain
        wait_lgkm0();
        bar_nodrain();

        // zero-fill stores: fire-and-forget, drain under the tile loop
        {
            const size_t zb = (size_t)blockIdx.x * ZPB + (size_t)cc * 4096 + tid;
#pragma unroll
            for (int z = 0; z < 16; ++z)
                outz[zb + z * 256] = zf;
        }

        const int base = (n << 2) + qs;
        const int a0   = seg * SW + cc * CCOL + (q << 2);   // col of acc[0] at tile 0
#pragma unroll 2
        for (int t = 0; t < TPC; ++t) {
            const s8v jb1 = lds[t * 64 + base];
            const s8v jb2 = lds[1024 + t * 64 + base];

            f4v acc = {0.f, 0.f, 0.f, 0.f};
            acc = __builtin_amdgcn_mfma_f32_16x16x32_bf16(jb1, i1, acc, 0, 0, 0);
            acc = __builtin_amdgcn_mfma_f32_16x16x32_bf16(jb2, i2, acc, 0, 0, 0);
            acc = __builtin_amdgcn_mfma_f32_16x16x32_bf16(jb1, i3, acc, 0, 0, 0);

            // exact (v desc, j asc) keys: tie in the 13 zero low-mantissa bits
            const int ca = a0 + (t << 4);
            double kd[4];
#pragma unroll
            for (int g = 0; g < 4; ++g) {
                const float v = acc[g];
                const int ja  = ca + g;
                const int tie = (v < 0.f) ? ja : (NN - 1 - ja);
                kd[g] = __longlong_as_double(__double_as_longlong((double)v) |
                                             (long long)(unsigned)tie);
            }

            // sort 4 keys desc (5 comparators)
            double s0 = kd[0], s1 = kd[1], s2 = kd[2], s3 = kd[3];
            CSWPS(s0, s1) CSWPS(s2, s3) CSWPS(s0, s2) CSWPS(s1, s3) CSWPS(s1, s2)

            // bitonic top-8 merge of sorted-8 L and sorted-4 {s0..s3}
            L[4] = fmax(L[4], s3);
            L[5] = fmax(L[5], s2);
            L[6] = fmax(L[6], s1);
            L[7] = fmax(L[7], s0);
            BSTAGESD(L)
        }
    }

    // quad merge across the 4 lanes of this row
#pragma unroll
    for (int mm = 16; mm <= 32; mm <<= 1) {
        double o[8], X[8];
#pragma unroll
        for (int t = 0; t < 8; ++t) o[t] = __shfl_xor(L[t], mm, 64);
#pragma unroll
        for (int t = 0; t < 8; ++t) X[t] = fmax(L[t], o[7 - t]);
        BSTAGESD(X)
#pragma unroll
        for (int t = 0; t < 8; ++t) L[t] = X[t];
    }

    if (q == 0) {
        double* dst = tqd + ((size_t)seg * NN + (row0 + n)) * 8;
#pragma unroll
        for (int t = 0; t < 8; ++t) dst[t] = L[t];
    }
}

// ---------------------------------------------------------------------------
// p2_merge: ONE WAVE PER ROW. 64 candidate keys (8 segs x top-8) <-> 64 lanes.
// 7 rounds of butterfly shfl-max; round 0 = self (dropped); rounds 1..6
// decode (v, j) and emit neighbors. Folds rowsum: winner lane adds rs[j],
// lane0 adds the own-row half-sum.
// ---------------------------------------------------------------------------
__global__ __launch_bounds__(256) void p2_merge(const double* __restrict__ tqd,
                                                float* __restrict__ rs,
                                                int* __restrict__ ni,
                                                float* __restrict__ nv)
{
    const int lane = threadIdx.x & 63;
    const int wv   = threadIdx.x >> 6;
    const int row  = blockIdx.x * 4 + wv;
    const int s    = lane >> 3;
    const int t    = lane & 7;

    double key = tqd[((size_t)s * NN + row) * 8 + t];
    float sum = 0.f;

#pragma unroll
    for (int r = 0; r < 7; ++r) {
        double m = key;
#pragma unroll
        for (int mm = 1; mm < 64; mm <<= 1) {
            const double o = __shfl_xor(m, mm, 64);
            m = fmax(m, o);
        }
        const long long mb = __double_as_longlong(m);
        if (r >= 1) {
            const float v  = (float)__longlong_as_double(mb & ~0x1FFFLL);
            const int tie  = (int)(mb & 0x1FFFLL);
            const int j    = (v < 0.f) ? tie : (NN - 1 - tie);
            sum += v;
            if (__double_as_longlong(key) == mb) {      // unique winner lane
                nv[(size_t)row * KN + (r - 1)] = v;
                ni[(size_t)row * KN + (r - 1)] = j;
                atomicAdd(&rs[j], 0.5f * v);
            }
        }
        if (__double_as_longlong(key) == mb)
            key = __longlong_as_double((long long)0xFFF0000000000000LL); // -inf
    }

    if (lane == 0) atomicAdd(&rs[row], 0.5f * sum);
}

// ---------------------------------------------------------------------------
// k5: scatter normalized values into pre-zeroed dense output
// ---------------------------------------------------------------------------
__global__ __launch_bounds__(256) void k5_scatter(const int* __restrict__ nbr_idx,
                                                  const float* __restrict__ nbr_val,
                                                  const float* __restrict__ rs,
                                                  float* __restrict__ out)
{
    const int e = blockIdx.x * 256 + threadIdx.x;
    const int i = e / KN;
    const int j = nbr_idx[e];
    const float v = nbr_val[e] * 0.5f;
    const float wi = v / (rs[i] + 1e-8f);
    const float wj = v / (rs[j] + 1e-8f);
    atomicAdd(out + (size_t)i * NN + j, wi);
    atomicAdd(out + (size_t)j * NN + i, wj);
}

// ---------------------------------------------------------------------------
extern "C" void kernel_launch(void* const* d_in, const int* in_sizes, int n_in,
                              void* d_out, int out_size, void* d_ws, size_t ws_size,
                              hipStream_t stream)
{
    const float* x = (const float*)d_in[0];   // 8192 x 256
    const float* W = (const float*)d_in[1];   // 16 x 256
    const float* b = (const float*)d_in[2];   // 16
    float* out = (float*)d_out;               // 8192 x 8192

    // workspace layout (~7 MB), doubles first for 8B alignment
    double* tqd  = (double*)d_ws;                     // SEG*NN*8 keys (4 MB)
    float*  rs   = (float*)(tqd + (size_t)SEG * NN * 8);  // NN
    float*  nv   = rs + NN;                           // NN*KN
    int*    ni   = (int*)(nv + (size_t)NN * KN);      // NN*KN
    ushort* PA1  = (ushort*)(ni + (size_t)NN * KN);   // NN*32 each
    ushort* PA2  = PA1 + (size_t)NN * 32;
    ushort* PA3  = PA2 + (size_t)NN * 32;
    ushort* PB1  = PA3 + (size_t)NN * 32;
    ushort* PB2  = PB1 + (size_t)NN * 32;

    k1_embed <<<NN / 4,           256, 0, stream>>>(x, W, b, rs, PA1, PA2, PA3, PB1, PB2);
    p1_scan  <<<(NN / 64) * SEG,  256, 0, stream>>>(PA1, PA2, PA3, PB1, PB2, tqd, (float4*)out);
    p2_merge <<<NN / 4,           256, 0, stream>>>(tqd, rs, ni, nv);
    k5_scatter<<<(NN * KN) / 256, 256, 0, stream>>>(ni, nv, rs, out);
}